// Round 8
// baseline (275.348 us; speedup 1.0000x reference)
//
#include <hip/hip_runtime.h>
#include <math.h>

namespace {

constexpr int B    = 128;
constexpr int H    = 1024;
constexpr int V    = 32000;
constexpr int WSZ  = 10;
constexpr int MAXW = 2 * WSZ + 1;   // 21

typedef __attribute__((ext_vector_type(8))) short bf16x8;
typedef __attribute__((ext_vector_type(4))) short short4v;
typedef __attribute__((ext_vector_type(4))) float f32x4;

__device__ __forceinline__ float sigf(float x) { return 1.0f / (1.0f + expf(-x)); }

__device__ __forceinline__ unsigned short rnebf(float f) {
    unsigned u = __float_as_uint(f);
    u += 0x7fffu + ((u >> 16) & 1u);
    return (unsigned short)(u >> 16);
}

__device__ __forceinline__ bf16x8 cvt8(const f32x4 a, const f32x4 b) {
    bf16x8 r;
    r[0] = (short)rnebf(a.x); r[1] = (short)rnebf(a.y);
    r[2] = (short)rnebf(a.z); r[3] = (short)rnebf(a.w);
    r[4] = (short)rnebf(b.x); r[5] = (short)rnebf(b.y);
    r[6] = (short)rnebf(b.z); r[7] = (short)rnebf(b.w);
    return r;
}

struct S3 { short h, m, l; };

// exact 3-way truncation split: x == h + m + l + delta, |delta| <~ 2^-24 |x|
__device__ __forceinline__ S3 split3(float x) {
    S3 r;
    const unsigned uh = __float_as_uint(x) & 0xFFFF0000u;
    const float fh = __uint_as_float(uh);
    const float r1 = x - fh;
    const unsigned um = __float_as_uint(r1) & 0xFFFF0000u;
    const float fm = __uint_as_float(um);
    const float r2 = r1 - fm;
    const unsigned ul = __float_as_uint(r2) & 0xFFFF0000u;
    r.h = (short)(uh >> 16);
    r.m = (short)(um >> 16);
    r.l = (short)(ul >> 16);
    return r;
}

__device__ __forceinline__ void split8(const f32x4 a, const f32x4 b,
                                       bf16x8& wh, bf16x8& wm, bf16x8& wl) {
    S3 s;
    s = split3(a.x); wh[0] = s.h; wm[0] = s.m; wl[0] = s.l;
    s = split3(a.y); wh[1] = s.h; wm[1] = s.m; wl[1] = s.l;
    s = split3(a.z); wh[2] = s.h; wm[2] = s.m; wl[2] = s.l;
    s = split3(a.w); wh[3] = s.h; wm[3] = s.m; wl[3] = s.l;
    s = split3(b.x); wh[4] = s.h; wm[4] = s.m; wl[4] = s.l;
    s = split3(b.y); wh[5] = s.h; wm[5] = s.m; wl[5] = s.l;
    s = split3(b.z); wh[6] = s.h; wm[6] = s.m; wl[6] = s.l;
    s = split3(b.w); wh[7] = s.h; wm[7] = s.m; wl[7] = s.l;
}

// ---------------------------------------------------------------------------
// fc2 split-K: part[y][128 x 32000] = A(bf16 128x[k0:k0+512]) @ W[:, k0:+512]^T
// 16 cols/wave, 4 waves/block, grid (500, 2) = 1000 blocks = 4 blocks/CU.
// W 2-deep + A 1-deep register prefetch.
// ---------------------------------------------------------------------------
__global__ __launch_bounds__(256, 4) void fc2_gemm(
    const short* __restrict__ A, const float* __restrict__ W,
    float* __restrict__ outbase)
{
    const int t = threadIdx.x;
    const int lane = t & 63;
    const int wv = t >> 6;
    const int n0 = blockIdx.x * 64 + wv * 16;
    const int k0 = blockIdx.y * 512;
    float* out = outbase + (size_t)blockIdx.y * B * V;
    const int m16 = lane & 15;
    const int ko8 = (lane >> 4) * 8;

    const float* wp = W + (size_t)(n0 + m16) * 1024 + k0 + ko8;
    const short* ap = A + (size_t)m16 * 1024 + k0 + ko8;

    f32x4 acc[8] = {};
    f32x4 cwa = *(const f32x4*)(wp);      f32x4 cwb = *(const f32x4*)(wp + 4);
    f32x4 nwa = *(const f32x4*)(wp + 32); f32x4 nwb = *(const f32x4*)(wp + 36);
    bf16x8 ca[8], na[8];
    #pragma unroll
    for (int m = 0; m < 8; ++m) {
        ca[m] = *(const bf16x8*)(ap + (size_t)m * 16384);
        na[m] = *(const bf16x8*)(ap + (size_t)m * 16384 + 32);
    }

    for (int kc = 0; kc + 64 < 512; kc += 32) {
        const int kf = kc + 64;
        const f32x4 fwa = *(const f32x4*)(wp + kf);
        const f32x4 fwb = *(const f32x4*)(wp + kf + 4);
        bf16x8 fa[8];
        #pragma unroll
        for (int m = 0; m < 8; ++m)
            fa[m] = *(const bf16x8*)(ap + (size_t)m * 16384 + kf);

        const bf16x8 b0 = cvt8(cwa, cwb);
        #pragma unroll
        for (int m = 0; m < 8; ++m)
            acc[m] = __builtin_amdgcn_mfma_f32_16x16x32_bf16(ca[m], b0, acc[m], 0, 0, 0);

        cwa = nwa; cwb = nwb; nwa = fwa; nwb = fwb;
        #pragma unroll
        for (int m = 0; m < 8; ++m) { ca[m] = na[m]; na[m] = fa[m]; }
    }
    {
        const bf16x8 b0 = cvt8(cwa, cwb);
        #pragma unroll
        for (int m = 0; m < 8; ++m)
            acc[m] = __builtin_amdgcn_mfma_f32_16x16x32_bf16(ca[m], b0, acc[m], 0, 0, 0);
    }
    {
        const bf16x8 b0 = cvt8(nwa, nwb);
        #pragma unroll
        for (int m = 0; m < 8; ++m)
            acc[m] = __builtin_amdgcn_mfma_f32_16x16x32_bf16(na[m], b0, acc[m], 0, 0, 0);
    }

    #pragma unroll
    for (int m = 0; m < 8; ++m) {
        const int rbase = m * 16 + (lane >> 4) * 4;
        #pragma unroll
        for (int r = 0; r < 4; ++r)
            out[(size_t)(rbase + r) * V + n0 + m16] = acc[m][r];
    }
}

// ---------------------------------------------------------------------------
// Split-bf16 (near-fp32) MFMA GEMM. A: 128x1024 in 3 bf16 planes. W: fp32,
// row stride 1024. y: src = y>>ks_log2, k0 = (y & ((1<<ks_log2)-1)) * Ksz.
// LSTM: N=4096, Ksz=128, ks_log2=3, grid (64,16).
// attn t1pre: N=512, Ksz=64, ks_log2=4, grid (8,16).
// ---------------------------------------------------------------------------
__global__ __launch_bounds__(256, 3) void gemm_x3(
    const short* __restrict__ Ah0, const short* __restrict__ Am0, const short* __restrict__ Al0,
    const short* __restrict__ Ah1, const short* __restrict__ Am1, const short* __restrict__ Al1,
    const float* __restrict__ W0, const float* __restrict__ W1,
    int N, int Ksz, int ks_log2, float* __restrict__ outbase)
{
    const int y = blockIdx.y;
    const int src = y >> ks_log2;
    const short* Ah = src ? Ah1 : Ah0;
    const short* Am = src ? Am1 : Am0;
    const short* Al = src ? Al1 : Al0;
    const float* W  = src ? W1  : W0;
    const int k0 = (y & ((1 << ks_log2) - 1)) * Ksz;
    float* out = outbase + (size_t)y * 128 * N;

    const int t    = threadIdx.x;
    const int lane = t & 63;
    const int wv   = t >> 6;
    const int n0   = blockIdx.x * 64 + wv * 16;
    const int m16  = lane & 15;
    const int ko8  = (lane >> 4) * 8;

    const float* wp = W + (size_t)(n0 + m16) * 1024 + k0 + ko8;
    const size_t a0 = (size_t)m16 * 1024 + k0 + ko8;

    f32x4 acc[8] = {};

    f32x4 cwa = *(const f32x4*)(wp);      f32x4 cwb = *(const f32x4*)(wp + 4);
    f32x4 nwa = *(const f32x4*)(wp + 32); f32x4 nwb = *(const f32x4*)(wp + 36);

    #define X3_CHUNK(KC, WA, WB)                                                    \
    {                                                                               \
        bf16x8 wh, wm, wl;                                                          \
        split8(WA, WB, wh, wm, wl);                                                 \
        _Pragma("unroll")                                                           \
        for (int m = 0; m < 8; ++m) {                                               \
            const size_t ao = a0 + (size_t)m * 16384 + (KC);                        \
            const bf16x8 ah = *(const bf16x8*)(Ah + ao);                            \
            const bf16x8 am = *(const bf16x8*)(Am + ao);                            \
            const bf16x8 al = *(const bf16x8*)(Al + ao);                            \
            acc[m] = __builtin_amdgcn_mfma_f32_16x16x32_bf16(ah, wh, acc[m], 0, 0, 0); \
            acc[m] = __builtin_amdgcn_mfma_f32_16x16x32_bf16(ah, wm, acc[m], 0, 0, 0); \
            acc[m] = __builtin_amdgcn_mfma_f32_16x16x32_bf16(am, wh, acc[m], 0, 0, 0); \
            acc[m] = __builtin_amdgcn_mfma_f32_16x16x32_bf16(ah, wl, acc[m], 0, 0, 0); \
            acc[m] = __builtin_amdgcn_mfma_f32_16x16x32_bf16(am, wm, acc[m], 0, 0, 0); \
            acc[m] = __builtin_amdgcn_mfma_f32_16x16x32_bf16(al, wh, acc[m], 0, 0, 0); \
        }                                                                           \
    }

    for (int kc = 0; kc + 64 < Ksz; kc += 32) {
        const f32x4 fwa = *(const f32x4*)(wp + kc + 64);
        const f32x4 fwb = *(const f32x4*)(wp + kc + 68);
        X3_CHUNK(kc, cwa, cwb);
        cwa = nwa; cwb = nwb; nwa = fwa; nwb = fwb;
    }
    X3_CHUNK(Ksz - 64, cwa, cwb);
    X3_CHUNK(Ksz - 32, nwa, nwb);
    #undef X3_CHUNK

    #pragma unroll
    for (int m = 0; m < 8; ++m) {
        const int rbase = m * 16 + (lane >> 4) * 4;
        #pragma unroll
        for (int r = 0; r < 4; ++r)
            out[(size_t)(rbase + r) * N + n0 + m16] = acc[m][r];
    }
}

// ---------------------------------------------------------------------------
// fc1: 32 split-K partials. y in [0,32): src=y>>4, k0=(y&15)*64. W stride 2048.
// ---------------------------------------------------------------------------
__global__ __launch_bounds__(256) void fc1_gemm(
    const short* __restrict__ A0, const short* __restrict__ A1,
    const float* __restrict__ W, float* __restrict__ outbase)
{
    const int y = blockIdx.y;
    const int src = y >> 4;
    const short* A = src ? A1 : A0;
    const int k0 = (y & 15) * 64;
    const int wk0 = src * 1024 + k0;
    float* out = outbase + (size_t)y * 128 * 1024;

    const int t    = threadIdx.x;
    const int lane = t & 63;
    const int wv   = t >> 6;
    const int n0   = blockIdx.x * 64 + wv * 16;
    const int m16  = lane & 15;
    const int ko8  = (lane >> 4) * 8;

    const float* wp = W + (size_t)(n0 + m16) * 2048 + wk0 + ko8;
    const short* ap = A + (size_t)m16 * 1024 + k0 + ko8;

    f32x4 acc[8] = {};
    const f32x4 cwa = *(const f32x4*)(wp);      const f32x4 cwb = *(const f32x4*)(wp + 4);
    const f32x4 nwa = *(const f32x4*)(wp + 32); const f32x4 nwb = *(const f32x4*)(wp + 36);

    {
        const bf16x8 bfr = cvt8(cwa, cwb);
        #pragma unroll
        for (int m = 0; m < 8; ++m) {
            const bf16x8 afr = *(const bf16x8*)(ap + (size_t)m * 16384);
            acc[m] = __builtin_amdgcn_mfma_f32_16x16x32_bf16(afr, bfr, acc[m], 0, 0, 0);
        }
    }
    {
        const bf16x8 bfr = cvt8(nwa, nwb);
        #pragma unroll
        for (int m = 0; m < 8; ++m) {
            const bf16x8 afr = *(const bf16x8*)(ap + (size_t)m * 16384 + 32);
            acc[m] = __builtin_amdgcn_mfma_f32_16x16x32_bf16(afr, bfr, acc[m], 0, 0, 0);
        }
    }

    #pragma unroll
    for (int m = 0; m < 8; ++m) {
        const int rbase = m * 16 + (lane >> 4) * 4;
        #pragma unroll
        for (int r = 0; r < 4; ++r)
            out[(size_t)(rbase + r) * 1024 + n0 + m16] = acc[m][r];
    }
}

// ---------------------------------------------------------------------------
// prep: embed lookup + split3 (blocks 0..127) and h0 split3 (blocks 128..383)
__global__ void prep_k(const int* __restrict__ word, const float* __restrict__ emb,
                       const float* __restrict__ h0,
                       short* __restrict__ xh, short* __restrict__ xm, short* __restrict__ xl,
                       short* __restrict__ h0h, short* __restrict__ h0m, short* __restrict__ h0l)
{
    const int blk = blockIdx.x, t = threadIdx.x;
    const float* src; short *dh, *dm, *dl; size_t off;
    if (blk < 128) {
        src = emb + (size_t)word[blk] * H; off = (size_t)blk * H;
        dh = xh; dm = xm; dl = xl;
    } else {
        const int i = blk - 128;
        src = h0 + (size_t)i * H; off = (size_t)i * H;
        dh = h0h; dm = h0m; dl = h0l;
    }
    const float4 v = ((const float4*)src)[t];
    short4v sh, sm, sl;
    S3 s;
    s = split3(v.x); sh.x = s.h; sm.x = s.m; sl.x = s.l;
    s = split3(v.y); sh.y = s.h; sm.y = s.m; sl.y = s.l;
    s = split3(v.z); sh.z = s.h; sm.z = s.m; sl.z = s.l;
    s = split3(v.w); sh.w = s.h; sm.w = s.m; sl.w = s.l;
    *(short4v*)(dh + off + t * 4) = sh;
    *(short4v*)(dm + off + t * 4) = sm;
    *(short4v*)(dl + off + t * 4) = sl;
}

// sum 16 partials + biases -> LSTM cell -> h (fp32), c (fp32), x splits (bf16)
__global__ void lstm_cell_k(const float* __restrict__ part,
                            const float* __restrict__ bih, const float* __restrict__ bhh,
                            const float* __restrict__ c0,
                            float* __restrict__ h_out, float* __restrict__ c_out,
                            short* __restrict__ xh, short* __restrict__ xm,
                            short* __restrict__ xl)
{
    const int idx = blockIdx.x * 256 + threadIdx.x;   // < 128*1024
    const int b = idx >> 10, hh = idx & 1023;
    const size_t base = (size_t)b * 4096;
    float g[4];
    #pragma unroll
    for (int j = 0; j < 4; ++j) {
        const int o = hh + j * H;
        float s = bih[o] + bhh[o];
        #pragma unroll
        for (int i = 0; i < 16; ++i) s += part[base + o + (size_t)i * 524288];
        g[j] = s;
    }
    const float c = sigf(g[1]) * c0[idx] + sigf(g[0]) * tanhf(g[2]);
    const float h = sigf(g[3]) * tanhf(c);
    c_out[idx] = c;
    h_out[idx] = h;
    const S3 s = split3(h);
    xh[idx] = s.h; xm[idx] = s.m; xl[idx] = s.l;
}

// fused: finish p from 16 t1pre partials -> window -> scores -> softmax*gauss
// -> a (out) and ctx (bf16)
__global__ void attn_ctx_k(const float* __restrict__ part, const float* __restrict__ b1,
                           const float* __restrict__ w2v, const float* __restrict__ b2,
                           const int* __restrict__ Sptr,
                           const float* __restrict__ x, const float* __restrict__ enc,
                           float* __restrict__ a_out, short* __restrict__ ctxb)
{
    __shared__ float red[256];
    __shared__ float so[H];
    __shared__ float swred[4][MAXW];
    __shared__ float ssc[MAXW];
    __shared__ float sa[MAXW];
    __shared__ float sp;
    __shared__ int sw0, sw1;
    const int b = blockIdx.x, t = threadIdx.x;
    const int lane = t & 63, wvv = t >> 6;

    {
        const float* pa = part + (size_t)b * 512;
        float v = 0.f;
        #pragma unroll
        for (int jj = 0; jj < 2; ++jj) {
            const int j = t + jj * 256;
            float sgm = b1[j];
            #pragma unroll
            for (int i = 0; i < 16; ++i) sgm += pa[j + (size_t)i * 65536];
            v += tanhf(sgm) * w2v[j];
        }
        red[t] = v;
        __syncthreads();
        for (int s = 128; s > 0; s >>= 1) {
            if (t < s) red[t] += red[t + s];
            __syncthreads();
        }
        if (t == 0) {
            const float S = (float)Sptr[0];
            const float sv = S * sigf(red[0] + b2[0]);
            sp  = sv;
            sw0 = (int)rintf(fmaxf(sv - (float)WSZ, 0.f));
            sw1 = (int)rintf(fminf(sv + (float)WSZ, S - 1.f));
        }
    }
    for (int h = t; h < H; h += 256) so[h] = x[(size_t)b * H + h];
    __syncthreads();
    const int w0 = sw0, w1e = sw1;
    const float pbv = sp;

    float ps[MAXW];
    #pragma unroll
    for (int w = 0; w < MAXW; ++w) ps[w] = 0.f;
    for (int h4 = t; h4 < H / 4; h4 += 256) {
        const float4 o = ((const float4*)so)[h4];
        #pragma unroll
        for (int w = 0; w < MAXW; ++w) {
            const int idx = w0 + w;
            if (idx <= w1e) {
                const float4 e = *(const float4*)(enc + ((size_t)idx * B + b) * H + h4 * 4);
                ps[w] += o.x * e.x + o.y * e.y + o.z * e.z + o.w * e.w;
            }
        }
    }
    #pragma unroll
    for (int w = 0; w < MAXW; ++w) {
        float v = ps[w];
        for (int off = 32; off > 0; off >>= 1) v += __shfl_down(v, off);
        if (lane == 0) swred[wvv][w] = v;
    }
    __syncthreads();
    if (t == 0) {
        float m = -1e30f;
        for (int w = 0; w < MAXW; ++w) {
            const float s = swred[0][w] + swred[1][w] + swred[2][w] + swred[3][w];
            ssc[w] = s;
            m = fmaxf(m, s);
        }
        float den = 0.f;
        for (int w = 0; w < MAXW; ++w) den += expf(ssc[w] - m);
        for (int w = 0; w < MAXW; ++w) {
            const int idx = w0 + w;
            const float gauss = (idx <= w1e) ? expf(((float)idx - pbv) / 50.0f) : 0.f;
            sa[w] = expf(ssc[w] - m) / den * gauss;
        }
    }
    __syncthreads();
    if (t < MAXW) a_out[b * MAXW + t] = sa[t];
    for (int h4 = t; h4 < H / 4; h4 += 256) {
        float4 acc = {0.f, 0.f, 0.f, 0.f};
        #pragma unroll
        for (int w = 0; w < MAXW; ++w) {
            const int idx = w0 + w;
            if (idx <= w1e) {
                const float4 e = *(const float4*)(enc + ((size_t)idx * B + b) * H + h4 * 4);
                acc.x += sa[w] * e.x; acc.y += sa[w] * e.y;
                acc.z += sa[w] * e.z; acc.w += sa[w] * e.w;
            }
        }
        short4v s;
        s.x = (short)rnebf(acc.x); s.y = (short)rnebf(acc.y);
        s.z = (short)rnebf(acc.z); s.w = (short)rnebf(acc.w);
        *(short4v*)(ctxb + (size_t)b * H + h4 * 4) = s;
    }
}

// sum 32 fc1 partials + bias -> tanh -> o2 (fp32, d_out) + o2b (bf16)
__global__ void fc1_fin_k(const float* __restrict__ part, const float* __restrict__ bias,
                          float* __restrict__ o2, short* __restrict__ o2b)
{
    const int idx = blockIdx.x * 256 + threadIdx.x;   // < 128*1024
    const int n = idx & 1023;
    float v = bias[n];
    #pragma unroll
    for (int i = 0; i < 32; ++i) v += part[idx + (size_t)i * 131072];
    v = tanhf(v);
    o2[idx] = v;
    o2b[idx] = (short)rnebf(v);
}

// fused fc2-finish + log_softmax: row = p0 + p1 + bias held in registers.
__global__ __launch_bounds__(1024) void lsm_k(
    const float* __restrict__ p0, const float* __restrict__ p1,
    const float* __restrict__ bias, float* __restrict__ y)
{
    __shared__ float sm[16], ss[16], slse;
    const int b = blockIdx.x, t = threadIdx.x;
    const float* r0 = p0 + (size_t)b * V;
    const float* r1 = p1 + (size_t)b * V;
    float* yrow = y + (size_t)b * V;

    f32x4 r[8];
    float m = -1e30f, s = 0.f;
    #pragma unroll
    for (int i = 0; i < 8; ++i) {
        const int v4 = t + i * 1024;
        if (v4 < V / 4) {
            const f32x4 a = ((const f32x4*)r0)[v4];
            const f32x4 c = ((const f32x4*)r1)[v4];
            const f32x4 bv = ((const f32x4*)bias)[v4];
            f32x4 q;
            q.x = a.x + c.x + bv.x; q.y = a.y + c.y + bv.y;
            q.z = a.z + c.z + bv.z; q.w = a.w + c.w + bv.w;
            r[i] = q;
            const float mm = fmaxf(fmaxf(q.x, q.y), fmaxf(q.z, q.w));
            if (mm > m) { s *= expf(m - mm); m = mm; }
            s += expf(q.x - m) + expf(q.y - m) + expf(q.z - m) + expf(q.w - m);
        }
    }
    for (int off = 32; off > 0; off >>= 1) {
        const float mo = __shfl_down(m, off), so = __shfl_down(s, off);
        const float mn = fmaxf(m, mo);
        s = s * expf(m - mn) + so * expf(mo - mn);
        m = mn;
    }
    const int wv = t >> 6, lane = t & 63;
    if (lane == 0) { sm[wv] = m; ss[wv] = s; }
    __syncthreads();
    if (t == 0) {
        float M = sm[0], S = ss[0];
        for (int i = 1; i < 16; ++i) {
            const float mn = fmaxf(M, sm[i]);
            S = S * expf(M - mn) + ss[i] * expf(sm[i] - mn);
            M = mn;
        }
        slse = M + logf(S);
    }
    __syncthreads();
    const float lse = slse;
    #pragma unroll
    for (int i = 0; i < 8; ++i) {
        const int v4 = t + i * 1024;
        if (v4 < V / 4) {
            f32x4 q = r[i];
            q.x -= lse; q.y -= lse; q.z -= lse; q.w -= lse;
            ((f32x4*)yrow)[v4] = q;
        }
    }
}

} // namespace

extern "C" void kernel_launch(void* const* d_in, const int* in_sizes, int n_in,
                              void* d_out, int out_size, void* d_ws, size_t ws_size,
                              hipStream_t stream)
{
    const int*   Sp   = (const int*)d_in[0];
    const float* enc  = (const float*)d_in[1];
    const int*   word = (const int*)d_in[2];
    const float* h0   = (const float*)d_in[3];
    const float* c0   = (const float*)d_in[4];
    const float* emb  = (const float*)d_in[5];
    const float* Wih  = (const float*)d_in[6];
    const float* Whh  = (const float*)d_in[7];
    const float* bih  = (const float*)d_in[8];
    const float* bhh  = (const float*)d_in[9];
    const float* aw1  = (const float*)d_in[10];
    const float* ab1  = (const float*)d_in[11];
    const float* aw2  = (const float*)d_in[12];
    const float* ab2  = (const float*)d_in[13];
    const float* f1w  = (const float*)d_in[14];
    const float* f1b  = (const float*)d_in[15];
    const float* f2w  = (const float*)d_in[16];
    const float* f2b  = (const float*)d_in[17];

    float* outp = (float*)d_out;
    float* y    = outp;                       // 128*32000
    float* o2   = y  + (size_t)B * V;         // 128*1024
    float* hN   = o2 + (size_t)B * H;         // 2*128*1024
    float* cN   = hN + 2 * (size_t)B * H;     // 2*128*1024
    float* aO   = cN + 2 * (size_t)B * H;     // 128*21

    char* wsp = (char*)d_ws;
    short* xh   = (short*)wsp;  wsp += (size_t)B * H * 2;
    short* xm   = (short*)wsp;  wsp += (size_t)B * H * 2;
    short* xl   = (short*)wsp;  wsp += (size_t)B * H * 2;
    short* h0h  = (short*)wsp;  wsp += (size_t)2 * B * H * 2;
    short* h0m  = (short*)wsp;  wsp += (size_t)2 * B * H * 2;
    short* h0l  = (short*)wsp;  wsp += (size_t)2 * B * H * 2;
    short* ctxb = (short*)wsp;  wsp += (size_t)B * H * 2;
    short* o2b  = (short*)wsp;  wsp += (size_t)B * H * 2;
    float* part = (float*)wsp;  wsp += (size_t)16 * B * 4 * H * 4;  // 32 MB
    float* pf2  = (float*)wsp;  wsp += (size_t)2 * B * V * 4;       // 32.8 MB

    prep_k<<<dim3(384), dim3(256), 0, stream>>>(word, emb, h0, xh, xm, xl, h0h, h0m, h0l);

    for (int l = 0; l < 2; ++l) {
        gemm_x3<<<dim3(64, 16), dim3(256), 0, stream>>>(
            xh, xm, xl,
            h0h + (size_t)l * B * H, h0m + (size_t)l * B * H, h0l + (size_t)l * B * H,
            Wih + (size_t)l * 4 * H * H, Whh + (size_t)l * 4 * H * H,
            4 * H, 128, 3, part);
        lstm_cell_k<<<dim3(B * H / 256), dim3(256), 0, stream>>>(
            part, bih + (size_t)l * 4 * H, bhh + (size_t)l * 4 * H,
            c0 + (size_t)l * B * H,
            hN + (size_t)l * B * H, cN + (size_t)l * B * H, xh, xm, xl);
    }

    const float* hfin = hN + (size_t)B * H;  // last layer h (fp32)

    // attn position pre-GEMM: t1pre = h @ w1^T (split3 MFMA, 16 K-partials)
    gemm_x3<<<dim3(8, 16), dim3(256), 0, stream>>>(
        xh, xm, xl, xh, xm, xl, aw1, aw1, 512, 64, 4, part);
    attn_ctx_k<<<dim3(B), dim3(256), 0, stream>>>(
        part, ab1, aw2, ab2, Sp, hfin, enc, aO, ctxb);

    // fc1: [ctx | out] @ f1w^T -> 32 split-K partials -> tanh
    fc1_gemm<<<dim3(16, 32), dim3(256), 0, stream>>>(ctxb, xh, f1w, part);
    fc1_fin_k<<<dim3(B * H / 256), dim3(256), 0, stream>>>(part, f1b, o2, o2b);

    // fc2: o2 @ f2w^T -> 2 K-partials
    fc2_gemm<<<dim3(V / 64, 2), dim3(256), 0, stream>>>(o2b, f2w, pf2);

    // fused fc2-finish (+bias) and log_softmax
    lsm_k<<<dim3(B), dim3(1024), 0, stream>>>(pf2, pf2 + (size_t)B * V, f2b, y);
}

// Round 9
// 263.901 us; speedup vs baseline: 1.0434x; 1.0434x over previous
//
#include <hip/hip_runtime.h>
#include <math.h>

namespace {

constexpr int B    = 128;
constexpr int H    = 1024;
constexpr int V    = 32000;
constexpr int WSZ  = 10;
constexpr int MAXW = 2 * WSZ + 1;   // 21

typedef __attribute__((ext_vector_type(8))) short bf16x8;
typedef __attribute__((ext_vector_type(4))) short short4v;
typedef __attribute__((ext_vector_type(4))) float f32x4;

__device__ __forceinline__ float sigf(float x) { return 1.0f / (1.0f + expf(-x)); }

__device__ __forceinline__ unsigned short rnebf(float f) {
    unsigned u = __float_as_uint(f);
    u += 0x7fffu + ((u >> 16) & 1u);
    return (unsigned short)(u >> 16);
}

__device__ __forceinline__ bf16x8 cvt8(const f32x4 a, const f32x4 b) {
    bf16x8 r;
    r[0] = (short)rnebf(a.x); r[1] = (short)rnebf(a.y);
    r[2] = (short)rnebf(a.z); r[3] = (short)rnebf(a.w);
    r[4] = (short)rnebf(b.x); r[5] = (short)rnebf(b.y);
    r[6] = (short)rnebf(b.z); r[7] = (short)rnebf(b.w);
    return r;
}

// async 16B global -> LDS (gfx950 global_load_lds dwordx4)
__device__ __forceinline__ void gl_lds16(const float* g, float* l) {
    __builtin_amdgcn_global_load_lds(
        (const __attribute__((address_space(1))) unsigned int*)g,
        (__attribute__((address_space(3))) unsigned int*)l,
        16, 0, 0);
}

struct S3 { short h, m, l; };

// exact 3-way truncation split: x == h + m + l + delta, |delta| <~ 2^-24 |x|
__device__ __forceinline__ S3 split3(float x) {
    S3 r;
    const unsigned uh = __float_as_uint(x) & 0xFFFF0000u;
    const float fh = __uint_as_float(uh);
    const float r1 = x - fh;
    const unsigned um = __float_as_uint(r1) & 0xFFFF0000u;
    const float fm = __uint_as_float(um);
    const float r2 = r1 - fm;
    const unsigned ul = __float_as_uint(r2) & 0xFFFF0000u;
    r.h = (short)(uh >> 16);
    r.m = (short)(um >> 16);
    r.l = (short)(ul >> 16);
    return r;
}

__device__ __forceinline__ void split8(const f32x4 a, const f32x4 b,
                                       bf16x8& wh, bf16x8& wm, bf16x8& wl) {
    S3 s;
    s = split3(a.x); wh[0] = s.h; wm[0] = s.m; wl[0] = s.l;
    s = split3(a.y); wh[1] = s.h; wm[1] = s.m; wl[1] = s.l;
    s = split3(a.z); wh[2] = s.h; wm[2] = s.m; wl[2] = s.l;
    s = split3(a.w); wh[3] = s.h; wm[3] = s.m; wl[3] = s.l;
    s = split3(b.x); wh[4] = s.h; wm[4] = s.m; wl[4] = s.l;
    s = split3(b.y); wh[5] = s.h; wm[5] = s.m; wl[5] = s.l;
    s = split3(b.z); wh[6] = s.h; wm[6] = s.m; wl[6] = s.l;
    s = split3(b.w); wh[7] = s.h; wm[7] = s.m; wl[7] = s.l;
}

// ---------------------------------------------------------------------------
// fc2 split-K with LDS-staged W (async global_load_lds, double buffer).
// part[y][128 x 32000] = A(bf16 128x[k0:k0+512]) @ W[:, k0:k0+512]^T
// Block: 256 thr (4 waves), 64 cols, K=512 in 8 chunks of 64.
// LDS per buffer: [issue 4][kg 4][col 64][4 f32] = 16 KB (kg staged by wave id).
// ---------------------------------------------------------------------------
__global__ __launch_bounds__(256) void fc2_gemm(
    const short* __restrict__ A, const float* __restrict__ W,
    float* __restrict__ outbase)
{
    __shared__ float wt[2][4096];   // 2 x 16 KB

    const int t    = threadIdx.x;
    const int lane = t & 63;
    const int w    = t >> 6;
    const int n0   = blockIdx.x * 64;
    const int k0   = blockIdx.y * 512;
    float* out = outbase + (size_t)blockIdx.y * B * V;
    const int m16  = lane & 15;
    const int ko8  = (lane >> 4) * 8;
    const int col  = w * 16 + m16;

    // staging: issue i stages k = kc + i*16 + w*4 .. +3 for col=lane
    const float* wsrc = W + (size_t)(n0 + lane) * 1024 + k0 + w * 4;
    const short* ap   = A + (size_t)m16 * 1024 + k0 + ko8;

    f32x4 acc[8] = {};

    #define FC2_STAGE(BUF, KC)                                         \
    {                                                                  \
        _Pragma("unroll")                                              \
        for (int i = 0; i < 4; ++i)                                    \
            gl_lds16(wsrc + (KC) + i * 16, &wt[BUF][i * 1024 + w * 256]); \
    }

    FC2_STAGE(0, 0)
    int cur = 0;
    for (int c = 0; c < 8; ++c) {
        __syncthreads();                       // staging of wt[cur] complete
        if (c < 7) {
            if (cur == 0) FC2_STAGE(1, (c + 1) * 64)
            else          FC2_STAGE(0, (c + 1) * 64)
        }
        #pragma unroll
        for (int sub = 0; sub < 2; ++sub) {
            const int k8 = sub * 32 + ko8;     // lane's 8-float k start in chunk
            const int ii = k8 >> 4;
            const int kg = (k8 >> 2) & 3;
            const float* lp = &wt[cur][ii * 1024 + kg * 256 + col * 4];
            const f32x4 wa = *(const f32x4*)(lp);
            const f32x4 wb = *(const f32x4*)(lp + 256);
            const bf16x8 bfr = cvt8(wa, wb);
            const short* ap2 = ap + c * 64 + sub * 32;
            #pragma unroll
            for (int m = 0; m < 8; ++m) {
                const bf16x8 afr = *(const bf16x8*)(ap2 + (size_t)m * 16384);
                acc[m] = __builtin_amdgcn_mfma_f32_16x16x32_bf16(afr, bfr, acc[m], 0, 0, 0);
            }
        }
        cur ^= 1;
    }
    #undef FC2_STAGE

    #pragma unroll
    for (int m = 0; m < 8; ++m) {
        const int rbase = m * 16 + (lane >> 4) * 4;
        #pragma unroll
        for (int r = 0; r < 4; ++r)
            out[(size_t)(rbase + r) * V + n0 + col] = acc[m][r];
    }
}

// ---------------------------------------------------------------------------
// Split-bf16 (near-fp32) MFMA GEMM. A: 128x1024 in 3 bf16 planes. W: fp32,
// row stride 1024. y: src = y>>ks_log2, k0 = (y & ((1<<ks_log2)-1)) * Ksz.
// LSTM: N=4096, Ksz=256, ks_log2=2, grid (64,8).
// attn t1pre: N=512, Ksz=64, ks_log2=4, grid (8,16).
// 2-deep W prefetch, peeled tails.
// ---------------------------------------------------------------------------
__global__ __launch_bounds__(256, 2) void gemm_x3(
    const short* __restrict__ Ah0, const short* __restrict__ Am0, const short* __restrict__ Al0,
    const short* __restrict__ Ah1, const short* __restrict__ Am1, const short* __restrict__ Al1,
    const float* __restrict__ W0, const float* __restrict__ W1,
    int N, int Ksz, int ks_log2, float* __restrict__ outbase)
{
    const int y = blockIdx.y;
    const int src = y >> ks_log2;
    const short* Ah = src ? Ah1 : Ah0;
    const short* Am = src ? Am1 : Am0;
    const short* Al = src ? Al1 : Al0;
    const float* W  = src ? W1  : W0;
    const int k0 = (y & ((1 << ks_log2) - 1)) * Ksz;
    float* out = outbase + (size_t)y * 128 * N;

    const int t    = threadIdx.x;
    const int lane = t & 63;
    const int wv   = t >> 6;
    const int n0   = blockIdx.x * 64 + wv * 16;
    const int m16  = lane & 15;
    const int ko8  = (lane >> 4) * 8;

    const float* wp = W + (size_t)(n0 + m16) * 1024 + k0 + ko8;
    const size_t a0 = (size_t)m16 * 1024 + k0 + ko8;

    f32x4 acc[8] = {};

    f32x4 cwa = *(const f32x4*)(wp);      f32x4 cwb = *(const f32x4*)(wp + 4);
    f32x4 nwa = *(const f32x4*)(wp + 32); f32x4 nwb = *(const f32x4*)(wp + 36);

    #define X3_CHUNK(KC, WA, WB)                                                    \
    {                                                                               \
        bf16x8 wh, wm, wl;                                                          \
        split8(WA, WB, wh, wm, wl);                                                 \
        _Pragma("unroll")                                                           \
        for (int m = 0; m < 8; ++m) {                                               \
            const size_t ao = a0 + (size_t)m * 16384 + (KC);                        \
            const bf16x8 ah = *(const bf16x8*)(Ah + ao);                            \
            const bf16x8 am = *(const bf16x8*)(Am + ao);                            \
            const bf16x8 al = *(const bf16x8*)(Al + ao);                            \
            acc[m] = __builtin_amdgcn_mfma_f32_16x16x32_bf16(ah, wh, acc[m], 0, 0, 0); \
            acc[m] = __builtin_amdgcn_mfma_f32_16x16x32_bf16(ah, wm, acc[m], 0, 0, 0); \
            acc[m] = __builtin_amdgcn_mfma_f32_16x16x32_bf16(am, wh, acc[m], 0, 0, 0); \
            acc[m] = __builtin_amdgcn_mfma_f32_16x16x32_bf16(ah, wl, acc[m], 0, 0, 0); \
            acc[m] = __builtin_amdgcn_mfma_f32_16x16x32_bf16(am, wm, acc[m], 0, 0, 0); \
            acc[m] = __builtin_amdgcn_mfma_f32_16x16x32_bf16(al, wh, acc[m], 0, 0, 0); \
        }                                                                           \
    }

    for (int kc = 0; kc + 64 < Ksz; kc += 32) {
        const f32x4 fwa = *(const f32x4*)(wp + kc + 64);
        const f32x4 fwb = *(const f32x4*)(wp + kc + 68);
        X3_CHUNK(kc, cwa, cwb);
        cwa = nwa; cwb = nwb; nwa = fwa; nwb = fwb;
    }
    X3_CHUNK(Ksz - 64, cwa, cwb);
    X3_CHUNK(Ksz - 32, nwa, nwb);
    #undef X3_CHUNK

    #pragma unroll
    for (int m = 0; m < 8; ++m) {
        const int rbase = m * 16 + (lane >> 4) * 4;
        #pragma unroll
        for (int r = 0; r < 4; ++r)
            out[(size_t)(rbase + r) * N + n0 + m16] = acc[m][r];
    }
}

// ---------------------------------------------------------------------------
// fc1: 16 split-K partials. y in [0,16): src=y>>3, k0=(y&7)*128. W stride 2048.
// ---------------------------------------------------------------------------
__global__ __launch_bounds__(256) void fc1_gemm(
    const short* __restrict__ A0, const short* __restrict__ A1,
    const float* __restrict__ W, float* __restrict__ outbase)
{
    const int y = blockIdx.y;
    const int src = y >> 3;
    const short* A = src ? A1 : A0;
    const int k0 = (y & 7) * 128;
    const int wk0 = src * 1024 + k0;
    float* out = outbase + (size_t)y * 128 * 1024;

    const int t    = threadIdx.x;
    const int lane = t & 63;
    const int wv   = t >> 6;
    const int n0   = blockIdx.x * 64 + wv * 16;
    const int m16  = lane & 15;
    const int ko8  = (lane >> 4) * 8;

    const float* wp = W + (size_t)(n0 + m16) * 2048 + wk0 + ko8;
    const short* ap = A + (size_t)m16 * 1024 + k0 + ko8;

    f32x4 acc[8] = {};
    f32x4 cwa = *(const f32x4*)(wp);      f32x4 cwb = *(const f32x4*)(wp + 4);
    f32x4 nwa = *(const f32x4*)(wp + 32); f32x4 nwb = *(const f32x4*)(wp + 36);

    #define FC1_CHUNK(KC, WA, WB)                                                   \
    {                                                                               \
        const bf16x8 bfr = cvt8(WA, WB);                                            \
        _Pragma("unroll")                                                           \
        for (int m = 0; m < 8; ++m) {                                               \
            const bf16x8 afr = *(const bf16x8*)(ap + (size_t)m * 16384 + (KC));     \
            acc[m] = __builtin_amdgcn_mfma_f32_16x16x32_bf16(afr, bfr, acc[m], 0, 0, 0); \
        }                                                                           \
    }

    for (int kc = 0; kc + 64 < 128; kc += 32) {
        const f32x4 fwa = *(const f32x4*)(wp + kc + 64);
        const f32x4 fwb = *(const f32x4*)(wp + kc + 68);
        FC1_CHUNK(kc, cwa, cwb);
        cwa = nwa; cwb = nwb; nwa = fwa; nwb = fwb;
    }
    FC1_CHUNK(64, cwa, cwb);
    FC1_CHUNK(96, nwa, nwb);
    #undef FC1_CHUNK

    #pragma unroll
    for (int m = 0; m < 8; ++m) {
        const int rbase = m * 16 + (lane >> 4) * 4;
        #pragma unroll
        for (int r = 0; r < 4; ++r)
            out[(size_t)(rbase + r) * 1024 + n0 + m16] = acc[m][r];
    }
}

// ---------------------------------------------------------------------------
// prep: embed lookup + split3 (blocks 0..127) and h0 split3 (blocks 128..383)
__global__ void prep_k(const int* __restrict__ word, const float* __restrict__ emb,
                       const float* __restrict__ h0,
                       short* __restrict__ xh, short* __restrict__ xm, short* __restrict__ xl,
                       short* __restrict__ h0h, short* __restrict__ h0m, short* __restrict__ h0l)
{
    const int blk = blockIdx.x, t = threadIdx.x;
    const float* src; short *dh, *dm, *dl; size_t off;
    if (blk < 128) {
        src = emb + (size_t)word[blk] * H; off = (size_t)blk * H;
        dh = xh; dm = xm; dl = xl;
    } else {
        const int i = blk - 128;
        src = h0 + (size_t)i * H; off = (size_t)i * H;
        dh = h0h; dm = h0m; dl = h0l;
    }
    const float4 v = ((const float4*)src)[t];
    short4v sh, sm, sl;
    S3 s;
    s = split3(v.x); sh.x = s.h; sm.x = s.m; sl.x = s.l;
    s = split3(v.y); sh.y = s.h; sm.y = s.m; sl.y = s.l;
    s = split3(v.z); sh.z = s.h; sm.z = s.m; sl.z = s.l;
    s = split3(v.w); sh.w = s.h; sm.w = s.m; sl.w = s.l;
    *(short4v*)(dh + off + t * 4) = sh;
    *(short4v*)(dm + off + t * 4) = sm;
    *(short4v*)(dl + off + t * 4) = sl;
}

// sum 8 partials + biases -> LSTM cell -> h (fp32), c (fp32), x splits (bf16)
__global__ void lstm_cell_k(const float* __restrict__ part,
                            const float* __restrict__ bih, const float* __restrict__ bhh,
                            const float* __restrict__ c0,
                            float* __restrict__ h_out, float* __restrict__ c_out,
                            short* __restrict__ xh, short* __restrict__ xm,
                            short* __restrict__ xl)
{
    const int idx = blockIdx.x * 256 + threadIdx.x;   // < 128*1024
    const int b = idx >> 10, hh = idx & 1023;
    const size_t base = (size_t)b * 4096;
    float g[4];
    #pragma unroll
    for (int j = 0; j < 4; ++j) {
        const int o = hh + j * H;
        float s = bih[o] + bhh[o];
        #pragma unroll
        for (int i = 0; i < 8; ++i) s += part[base + o + (size_t)i * 524288];
        g[j] = s;
    }
    const float c = sigf(g[1]) * c0[idx] + sigf(g[0]) * tanhf(g[2]);
    const float h = sigf(g[3]) * tanhf(c);
    c_out[idx] = c;
    h_out[idx] = h;
    const S3 s = split3(h);
    xh[idx] = s.h; xm[idx] = s.m; xl[idx] = s.l;
}

// fused: finish p from 16 t1pre partials -> window -> scores -> softmax*gauss
// -> a (out) and ctx (bf16)
__global__ void attn_ctx_k(const float* __restrict__ part, const float* __restrict__ b1,
                           const float* __restrict__ w2v, const float* __restrict__ b2,
                           const int* __restrict__ Sptr,
                           const float* __restrict__ x, const float* __restrict__ enc,
                           float* __restrict__ a_out, short* __restrict__ ctxb)
{
    __shared__ float red[256];
    __shared__ float so[H];
    __shared__ float swred[4][MAXW];
    __shared__ float ssc[MAXW];
    __shared__ float sa[MAXW];
    __shared__ float sp;
    __shared__ int sw0, sw1;
    const int b = blockIdx.x, t = threadIdx.x;
    const int lane = t & 63, wvv = t >> 6;

    {
        const float* pa = part + (size_t)b * 512;
        float v = 0.f;
        #pragma unroll
        for (int jj = 0; jj < 2; ++jj) {
            const int j = t + jj * 256;
            float sgm = b1[j];
            #pragma unroll
            for (int i = 0; i < 16; ++i) sgm += pa[j + (size_t)i * 65536];
            v += tanhf(sgm) * w2v[j];
        }
        red[t] = v;
        __syncthreads();
        for (int s = 128; s > 0; s >>= 1) {
            if (t < s) red[t] += red[t + s];
            __syncthreads();
        }
        if (t == 0) {
            const float S = (float)Sptr[0];
            const float sv = S * sigf(red[0] + b2[0]);
            sp  = sv;
            sw0 = (int)rintf(fmaxf(sv - (float)WSZ, 0.f));
            sw1 = (int)rintf(fminf(sv + (float)WSZ, S - 1.f));
        }
    }
    for (int h = t; h < H; h += 256) so[h] = x[(size_t)b * H + h];
    __syncthreads();
    const int w0 = sw0, w1e = sw1;
    const float pbv = sp;

    float ps[MAXW];
    #pragma unroll
    for (int w = 0; w < MAXW; ++w) ps[w] = 0.f;
    for (int h4 = t; h4 < H / 4; h4 += 256) {
        const float4 o = ((const float4*)so)[h4];
        #pragma unroll
        for (int w = 0; w < MAXW; ++w) {
            const int idx = w0 + w;
            if (idx <= w1e) {
                const float4 e = *(const float4*)(enc + ((size_t)idx * B + b) * H + h4 * 4);
                ps[w] += o.x * e.x + o.y * e.y + o.z * e.z + o.w * e.w;
            }
        }
    }
    #pragma unroll
    for (int w = 0; w < MAXW; ++w) {
        float v = ps[w];
        for (int off = 32; off > 0; off >>= 1) v += __shfl_down(v, off);
        if (lane == 0) swred[wvv][w] = v;
    }
    __syncthreads();
    if (t == 0) {
        float m = -1e30f;
        for (int w = 0; w < MAXW; ++w) {
            const float s = swred[0][w] + swred[1][w] + swred[2][w] + swred[3][w];
            ssc[w] = s;
            m = fmaxf(m, s);
        }
        float den = 0.f;
        for (int w = 0; w < MAXW; ++w) den += expf(ssc[w] - m);
        for (int w = 0; w < MAXW; ++w) {
            const int idx = w0 + w;
            const float gauss = (idx <= w1e) ? expf(((float)idx - pbv) / 50.0f) : 0.f;
            sa[w] = expf(ssc[w] - m) / den * gauss;
        }
    }
    __syncthreads();
    if (t < MAXW) a_out[b * MAXW + t] = sa[t];
    for (int h4 = t; h4 < H / 4; h4 += 256) {
        float4 acc = {0.f, 0.f, 0.f, 0.f};
        #pragma unroll
        for (int w = 0; w < MAXW; ++w) {
            const int idx = w0 + w;
            if (idx <= w1e) {
                const float4 e = *(const float4*)(enc + ((size_t)idx * B + b) * H + h4 * 4);
                acc.x += sa[w] * e.x; acc.y += sa[w] * e.y;
                acc.z += sa[w] * e.z; acc.w += sa[w] * e.w;
            }
        }
        short4v s;
        s.x = (short)rnebf(acc.x); s.y = (short)rnebf(acc.y);
        s.z = (short)rnebf(acc.z); s.w = (short)rnebf(acc.w);
        *(short4v*)(ctxb + (size_t)b * H + h4 * 4) = s;
    }
}

// sum 16 fc1 partials + bias -> tanh -> o2 (fp32, d_out) + o2b (bf16)
__global__ void fc1_fin_k(const float* __restrict__ part, const float* __restrict__ bias,
                          float* __restrict__ o2, short* __restrict__ o2b)
{
    const int idx = blockIdx.x * 256 + threadIdx.x;   // < 128*1024
    const int n = idx & 1023;
    float v = bias[n];
    #pragma unroll
    for (int i = 0; i < 16; ++i) v += part[idx + (size_t)i * 131072];
    v = tanhf(v);
    o2[idx] = v;
    o2b[idx] = (short)rnebf(v);
}

// fused fc2-finish + log_softmax: row = p0 + p1 + bias held in registers.
__global__ __launch_bounds__(1024) void lsm_k(
    const float* __restrict__ p0, const float* __restrict__ p1,
    const float* __restrict__ bias, float* __restrict__ y)
{
    __shared__ float sm[16], ss[16], slse;
    const int b = blockIdx.x, t = threadIdx.x;
    const float* r0 = p0 + (size_t)b * V;
    const float* r1 = p1 + (size_t)b * V;
    float* yrow = y + (size_t)b * V;

    f32x4 r[8];
    float m = -1e30f, s = 0.f;
    #pragma unroll
    for (int i = 0; i < 8; ++i) {
        const int v4 = t + i * 1024;
        if (v4 < V / 4) {
            const f32x4 a = ((const f32x4*)r0)[v4];
            const f32x4 c = ((const f32x4*)r1)[v4];
            const f32x4 bv = ((const f32x4*)bias)[v4];
            f32x4 q;
            q.x = a.x + c.x + bv.x; q.y = a.y + c.y + bv.y;
            q.z = a.z + c.z + bv.z; q.w = a.w + c.w + bv.w;
            r[i] = q;
            const float mm = fmaxf(fmaxf(q.x, q.y), fmaxf(q.z, q.w));
            if (mm > m) { s *= expf(m - mm); m = mm; }
            s += expf(q.x - m) + expf(q.y - m) + expf(q.z - m) + expf(q.w - m);
        }
    }
    for (int off = 32; off > 0; off >>= 1) {
        const float mo = __shfl_down(m, off), so = __shfl_down(s, off);
        const float mn = fmaxf(m, mo);
        s = s * expf(m - mn) + so * expf(mo - mn);
        m = mn;
    }
    const int wv = t >> 6, lane = t & 63;
    if (lane == 0) { sm[wv] = m; ss[wv] = s; }
    __syncthreads();
    if (t == 0) {
        float M = sm[0], S = ss[0];
        for (int i = 1; i < 16; ++i) {
            const float mn = fmaxf(M, sm[i]);
            S = S * expf(M - mn) + ss[i] * expf(sm[i] - mn);
            M = mn;
        }
        slse = M + logf(S);
    }
    __syncthreads();
    const float lse = slse;
    #pragma unroll
    for (int i = 0; i < 8; ++i) {
        const int v4 = t + i * 1024;
        if (v4 < V / 4) {
            f32x4 q = r[i];
            q.x -= lse; q.y -= lse; q.z -= lse; q.w -= lse;
            ((f32x4*)yrow)[v4] = q;
        }
    }
}

} // namespace

extern "C" void kernel_launch(void* const* d_in, const int* in_sizes, int n_in,
                              void* d_out, int out_size, void* d_ws, size_t ws_size,
                              hipStream_t stream)
{
    const int*   Sp   = (const int*)d_in[0];
    const float* enc  = (const float*)d_in[1];
    const int*   word = (const int*)d_in[2];
    const float* h0   = (const float*)d_in[3];
    const float* c0   = (const float*)d_in[4];
    const float* emb  = (const float*)d_in[5];
    const float* Wih  = (const float*)d_in[6];
    const float* Whh  = (const float*)d_in[7];
    const float* bih  = (const float*)d_in[8];
    const float* bhh  = (const float*)d_in[9];
    const float* aw1  = (const float*)d_in[10];
    const float* ab1  = (const float*)d_in[11];
    const float* aw2  = (const float*)d_in[12];
    const float* ab2  = (const float*)d_in[13];
    const float* f1w  = (const float*)d_in[14];
    const float* f1b  = (const float*)d_in[15];
    const float* f2w  = (const float*)d_in[16];
    const float* f2b  = (const float*)d_in[17];

    float* outp = (float*)d_out;
    float* y    = outp;                       // 128*32000
    float* o2   = y  + (size_t)B * V;         // 128*1024
    float* hN   = o2 + (size_t)B * H;         // 2*128*1024
    float* cN   = hN + 2 * (size_t)B * H;     // 2*128*1024
    float* aO   = cN + 2 * (size_t)B * H;     // 128*21

    char* wsp = (char*)d_ws;
    short* xh   = (short*)wsp;  wsp += (size_t)B * H * 2;
    short* xm   = (short*)wsp;  wsp += (size_t)B * H * 2;
    short* xl   = (short*)wsp;  wsp += (size_t)B * H * 2;
    short* h0h  = (short*)wsp;  wsp += (size_t)2 * B * H * 2;
    short* h0m  = (short*)wsp;  wsp += (size_t)2 * B * H * 2;
    short* h0l  = (short*)wsp;  wsp += (size_t)2 * B * H * 2;
    short* ctxb = (short*)wsp;  wsp += (size_t)B * H * 2;
    short* o2b  = (short*)wsp;  wsp += (size_t)B * H * 2;
    float* part = (float*)wsp;  wsp += (size_t)16 * B * 4 * H * 4;  // 32 MB
    float* pf2  = (float*)wsp;  wsp += (size_t)2 * B * V * 4;       // 32.8 MB

    prep_k<<<dim3(384), dim3(256), 0, stream>>>(word, emb, h0, xh, xm, xl, h0h, h0m, h0l);

    for (int l = 0; l < 2; ++l) {
        gemm_x3<<<dim3(64, 8), dim3(256), 0, stream>>>(
            xh, xm, xl,
            h0h + (size_t)l * B * H, h0m + (size_t)l * B * H, h0l + (size_t)l * B * H,
            Wih + (size_t)l * 4 * H * H, Whh + (size_t)l * 4 * H * H,
            4 * H, 256, 2, part);
        lstm_cell_k<<<dim3(B * H / 256), dim3(256), 0, stream>>>(
            part, bih + (size_t)l * 4 * H, bhh + (size_t)l * 4 * H,
            c0 + (size_t)l * B * H,
            hN + (size_t)l * B * H, cN + (size_t)l * B * H, xh, xm, xl);
    }

    const float* hfin = hN + (size_t)B * H;  // last layer h (fp32)

    // attn position pre-GEMM: t1pre = h @ w1^T (split3 MFMA, 16 K-partials)
    gemm_x3<<<dim3(8, 16), dim3(256), 0, stream>>>(
        xh, xm, xl, xh, xm, xl, aw1, aw1, 512, 64, 4, part);
    attn_ctx_k<<<dim3(B), dim3(256), 0, stream>>>(
        part, ab1, aw2, ab2, Sp, hfin, enc, aO, ctxb);

    // fc1: [ctx | out] @ f1w^T -> 16 split-K partials -> tanh
    fc1_gemm<<<dim3(16, 16), dim3(256), 0, stream>>>(ctxb, xh, f1w, part);
    fc1_fin_k<<<dim3(B * H / 256), dim3(256), 0, stream>>>(part, f1b, o2, o2b);

    // fc2: o2 @ f2w^T -> 2 K-partials (LDS-staged W)
    fc2_gemm<<<dim3(V / 64, 2), dim3(256), 0, stream>>>(o2b, f2w, pf2);

    // fused fc2-finish (+bias) and log_softmax
    lsm_k<<<dim3(B), dim3(1024), 0, stream>>>(pf2, pf2 + (size_t)B * V, f2b, y);
}

// Round 10
// 254.125 us; speedup vs baseline: 1.0835x; 1.0385x over previous
//
#include <hip/hip_runtime.h>
#include <math.h>

namespace {

constexpr int B    = 128;
constexpr int H    = 1024;
constexpr int V    = 32000;
constexpr int WSZ  = 10;
constexpr int MAXW = 2 * WSZ + 1;   // 21

typedef __attribute__((ext_vector_type(8))) short bf16x8;
typedef __attribute__((ext_vector_type(4))) short short4v;
typedef __attribute__((ext_vector_type(4))) float f32x4;

__device__ __forceinline__ float sigf(float x) { return 1.0f / (1.0f + expf(-x)); }

__device__ __forceinline__ unsigned short rnebf(float f) {
    unsigned u = __float_as_uint(f);
    u += 0x7fffu + ((u >> 16) & 1u);
    return (unsigned short)(u >> 16);
}

__device__ __forceinline__ bf16x8 cvt8(const f32x4 a, const f32x4 b) {
    bf16x8 r;
    r[0] = (short)rnebf(a.x); r[1] = (short)rnebf(a.y);
    r[2] = (short)rnebf(a.z); r[3] = (short)rnebf(a.w);
    r[4] = (short)rnebf(b.x); r[5] = (short)rnebf(b.y);
    r[6] = (short)rnebf(b.z); r[7] = (short)rnebf(b.w);
    return r;
}

// async 16B global -> LDS (gfx950 global_load_lds dwordx4)
__device__ __forceinline__ void gl_lds16(const float* g, float* l) {
    __builtin_amdgcn_global_load_lds(
        (const __attribute__((address_space(1))) unsigned int*)g,
        (__attribute__((address_space(3))) unsigned int*)l,
        16, 0, 0);
}

struct S3 { short h, m, l; };

// exact 3-way truncation split: x == h + m + l + delta, |delta| <~ 2^-24 |x|
__device__ __forceinline__ S3 split3(float x) {
    S3 r;
    const unsigned uh = __float_as_uint(x) & 0xFFFF0000u;
    const float fh = __uint_as_float(uh);
    const float r1 = x - fh;
    const unsigned um = __float_as_uint(r1) & 0xFFFF0000u;
    const float fm = __uint_as_float(um);
    const float r2 = r1 - fm;
    const unsigned ul = __float_as_uint(r2) & 0xFFFF0000u;
    r.h = (short)(uh >> 16);
    r.m = (short)(um >> 16);
    r.l = (short)(ul >> 16);
    return r;
}

__device__ __forceinline__ void split8(const f32x4 a, const f32x4 b,
                                       bf16x8& wh, bf16x8& wm, bf16x8& wl) {
    S3 s;
    s = split3(a.x); wh[0] = s.h; wm[0] = s.m; wl[0] = s.l;
    s = split3(a.y); wh[1] = s.h; wm[1] = s.m; wl[1] = s.l;
    s = split3(a.z); wh[2] = s.h; wm[2] = s.m; wl[2] = s.l;
    s = split3(a.w); wh[3] = s.h; wm[3] = s.m; wl[3] = s.l;
    s = split3(b.x); wh[4] = s.h; wm[4] = s.m; wl[4] = s.l;
    s = split3(b.y); wh[5] = s.h; wm[5] = s.m; wl[5] = s.l;
    s = split3(b.z); wh[6] = s.h; wm[6] = s.m; wl[6] = s.l;
    s = split3(b.w); wh[7] = s.h; wm[7] = s.m; wl[7] = s.l;
}

// ---------------------------------------------------------------------------
// fc2 split-K, LDS-staged W, COALESCED staging + piece-swizzle.
// part[y][128 x 32000] = A(bf16 128x[k0:+512]) @ W[:, k0:+512]^T
// Block: 256 thr (4 waves), 64 cols (= W rows), K=512 in 8 chunks of 64 floats.
// LDS buffer: [64 rows][64 floats] = 16 KB; LDS[r][piece s] = W piece s^(r&7)
// (16B pieces). Staging: thread t stages row t>>4 (+16/issue), src piece
// (t&15)^((t>>4)&7) -> wave writes 4 x 256B contiguous global segments.
// A-loads issued BEFORE staging so vmcnt waits don't drain the prefetch.
// ---------------------------------------------------------------------------
__global__ __launch_bounds__(256) void fc2_gemm(
    const short* __restrict__ A, const float* __restrict__ W,
    float* __restrict__ outbase)
{
    __shared__ float wt[2][4096];   // 2 x 16 KB

    const int t    = threadIdx.x;
    const int lane = t & 63;
    const int w    = t >> 6;
    const int n0   = blockIdx.x * 64;
    const int k0   = blockIdx.y * 512;
    float* out = outbase + (size_t)blockIdx.y * B * V;
    const int m16  = lane & 15;
    const int g    = lane >> 4;
    const int R    = w * 16 + m16;        // LDS row = out col within block

    // staging addressing
    const int rg = t >> 4;                // row 0..15 (+ i*16)
    const int ps = (t & 15) ^ (rg & 7);   // pre-swizzled source piece
    const float* wsrc = W + (size_t)(n0 + rg) * 1024 + k0 + ps * 4;
    const short* ap   = A + (size_t)m16 * 1024 + k0 + g * 8;

    f32x4 acc[8] = {};
    const int sxor = m16 & 7;

#define FC2_STAGE(BUF, KC)                                              \
    {                                                                   \
        _Pragma("unroll")                                               \
        for (int i = 0; i < 4; ++i)                                     \
            gl_lds16(wsrc + (KC) + (size_t)i * 16384,                   \
                     &wt[BUF][i * 1024 + w * 256]);                     \
    }

    FC2_STAGE(0, 0)
    int cur = 0;
    for (int c = 0; c < 8; ++c) {
        __syncthreads();                       // wt[cur] staged
        // A fragments for this chunk — issued BEFORE next staging
        bf16x8 a0[8], a1[8];
        #pragma unroll
        for (int m = 0; m < 8; ++m) {
            a0[m] = *(const bf16x8*)(ap + (size_t)m * 16384 + c * 64);
            a1[m] = *(const bf16x8*)(ap + (size_t)m * 16384 + c * 64 + 32);
        }
        __builtin_amdgcn_sched_barrier(0);
        if (c < 7) {
            if (cur == 0) FC2_STAGE(1, (c + 1) * 64)
            else          FC2_STAGE(0, (c + 1) * 64)
        }
        const float* lrow = &wt[cur][R * 64];
        #pragma unroll
        for (int sub = 0; sub < 2; ++sub) {
            const int p0 = sub * 8 + g * 2;
            const f32x4 wa = *(const f32x4*)(lrow + ((p0)     ^ sxor) * 4);
            const f32x4 wb = *(const f32x4*)(lrow + ((p0 + 1) ^ sxor) * 4);
            const bf16x8 bfr = cvt8(wa, wb);
            #pragma unroll
            for (int m = 0; m < 8; ++m) {
                acc[m] = __builtin_amdgcn_mfma_f32_16x16x32_bf16(
                    sub ? a1[m] : a0[m], bfr, acc[m], 0, 0, 0);
            }
        }
        cur ^= 1;
    }
#undef FC2_STAGE

    #pragma unroll
    for (int m = 0; m < 8; ++m) {
        const int rbase = m * 16 + g * 4;
        #pragma unroll
        for (int r = 0; r < 4; ++r)
            out[(size_t)(rbase + r) * V + n0 + R] = acc[m][r];
    }
}

// ---------------------------------------------------------------------------
// Split-bf16 (near-fp32) MFMA GEMM. A: 128x1024 in 3 bf16 planes. W: fp32,
// row stride 1024. y: src = y>>ks_log2, k0 = (y & ((1<<ks_log2)-1)) * Ksz.
// A-loads hoisted and issued BEFORE the W prefetch (vmcnt ordering).
// LSTM: N=4096, Ksz=256, ks_log2=2, grid (64,8).
// attn t1pre: N=512, Ksz=64, ks_log2=4, grid (8,16).
// ---------------------------------------------------------------------------
__global__ __launch_bounds__(256, 2) void gemm_x3(
    const short* __restrict__ Ah0, const short* __restrict__ Am0, const short* __restrict__ Al0,
    const short* __restrict__ Ah1, const short* __restrict__ Am1, const short* __restrict__ Al1,
    const float* __restrict__ W0, const float* __restrict__ W1,
    int N, int Ksz, int ks_log2, float* __restrict__ outbase)
{
    const int y = blockIdx.y;
    const int src = y >> ks_log2;
    const short* Ah = src ? Ah1 : Ah0;
    const short* Am = src ? Am1 : Am0;
    const short* Al = src ? Al1 : Al0;
    const float* W  = src ? W1  : W0;
    const int k0 = (y & ((1 << ks_log2) - 1)) * Ksz;
    float* out = outbase + (size_t)y * 128 * N;

    const int t    = threadIdx.x;
    const int lane = t & 63;
    const int wv   = t >> 6;
    const int n0   = blockIdx.x * 64 + wv * 16;
    const int m16  = lane & 15;
    const int ko8  = (lane >> 4) * 8;

    const float* wp = W + (size_t)(n0 + m16) * 1024 + k0 + ko8;
    const size_t a0 = (size_t)m16 * 1024 + k0 + ko8;

    f32x4 acc[8] = {};

    f32x4 cwa = *(const f32x4*)(wp);      f32x4 cwb = *(const f32x4*)(wp + 4);
    f32x4 nwa = *(const f32x4*)(wp + 32); f32x4 nwb = *(const f32x4*)(wp + 36);

    for (int kc = 0; kc + 64 < Ksz; kc += 32) {
        bf16x8 ah[8], am[8], al[8];
        #pragma unroll
        for (int m = 0; m < 8; ++m) {
            const size_t ao = a0 + (size_t)m * 16384 + kc;
            ah[m] = *(const bf16x8*)(Ah + ao);
            am[m] = *(const bf16x8*)(Am + ao);
            al[m] = *(const bf16x8*)(Al + ao);
        }
        __builtin_amdgcn_sched_barrier(0);
        const f32x4 fwa = *(const f32x4*)(wp + kc + 64);
        const f32x4 fwb = *(const f32x4*)(wp + kc + 68);
        bf16x8 wh, wm, wl;
        split8(cwa, cwb, wh, wm, wl);
        #pragma unroll
        for (int m = 0; m < 8; ++m) {
            acc[m] = __builtin_amdgcn_mfma_f32_16x16x32_bf16(ah[m], wh, acc[m], 0, 0, 0);
            acc[m] = __builtin_amdgcn_mfma_f32_16x16x32_bf16(ah[m], wm, acc[m], 0, 0, 0);
            acc[m] = __builtin_amdgcn_mfma_f32_16x16x32_bf16(am[m], wh, acc[m], 0, 0, 0);
            acc[m] = __builtin_amdgcn_mfma_f32_16x16x32_bf16(ah[m], wl, acc[m], 0, 0, 0);
            acc[m] = __builtin_amdgcn_mfma_f32_16x16x32_bf16(am[m], wm, acc[m], 0, 0, 0);
            acc[m] = __builtin_amdgcn_mfma_f32_16x16x32_bf16(al[m], wh, acc[m], 0, 0, 0);
        }
        cwa = nwa; cwb = nwb; nwa = fwa; nwb = fwb;
    }
    #pragma unroll
    for (int tail = 0; tail < 2; ++tail) {
        const int kc = Ksz - 64 + tail * 32;
        bf16x8 ah[8], am[8], al[8];
        #pragma unroll
        for (int m = 0; m < 8; ++m) {
            const size_t ao = a0 + (size_t)m * 16384 + kc;
            ah[m] = *(const bf16x8*)(Ah + ao);
            am[m] = *(const bf16x8*)(Am + ao);
            al[m] = *(const bf16x8*)(Al + ao);
        }
        const f32x4 wa = tail ? nwa : cwa;
        const f32x4 wb = tail ? nwb : cwb;
        bf16x8 wh, wm, wl;
        split8(wa, wb, wh, wm, wl);
        #pragma unroll
        for (int m = 0; m < 8; ++m) {
            acc[m] = __builtin_amdgcn_mfma_f32_16x16x32_bf16(ah[m], wh, acc[m], 0, 0, 0);
            acc[m] = __builtin_amdgcn_mfma_f32_16x16x32_bf16(ah[m], wm, acc[m], 0, 0, 0);
            acc[m] = __builtin_amdgcn_mfma_f32_16x16x32_bf16(am[m], wh, acc[m], 0, 0, 0);
            acc[m] = __builtin_amdgcn_mfma_f32_16x16x32_bf16(ah[m], wl, acc[m], 0, 0, 0);
            acc[m] = __builtin_amdgcn_mfma_f32_16x16x32_bf16(am[m], wm, acc[m], 0, 0, 0);
            acc[m] = __builtin_amdgcn_mfma_f32_16x16x32_bf16(al[m], wh, acc[m], 0, 0, 0);
        }
    }

    #pragma unroll
    for (int m = 0; m < 8; ++m) {
        const int rbase = m * 16 + (lane >> 4) * 4;
        #pragma unroll
        for (int r = 0; r < 4; ++r)
            out[(size_t)(rbase + r) * N + n0 + m16] = acc[m][r];
    }
}

// ---------------------------------------------------------------------------
// fc1: 16 split-K partials. y in [0,16): src=y>>3, k0=(y&7)*128. W stride 2048.
// ---------------------------------------------------------------------------
__global__ __launch_bounds__(256) void fc1_gemm(
    const short* __restrict__ A0, const short* __restrict__ A1,
    const float* __restrict__ W, float* __restrict__ outbase)
{
    const int y = blockIdx.y;
    const int src = y >> 3;
    const short* A = src ? A1 : A0;
    const int k0 = (y & 7) * 128;
    const int wk0 = src * 1024 + k0;
    float* out = outbase + (size_t)y * 128 * 1024;

    const int t    = threadIdx.x;
    const int lane = t & 63;
    const int wv   = t >> 6;
    const int n0   = blockIdx.x * 64 + wv * 16;
    const int m16  = lane & 15;
    const int ko8  = (lane >> 4) * 8;

    const float* wp = W + (size_t)(n0 + m16) * 2048 + wk0 + ko8;
    const short* ap = A + (size_t)m16 * 1024 + k0 + ko8;

    f32x4 acc[8] = {};

    #pragma unroll
    for (int kc = 0; kc < 128; kc += 32) {
        bf16x8 afr[8];
        #pragma unroll
        for (int m = 0; m < 8; ++m)
            afr[m] = *(const bf16x8*)(ap + (size_t)m * 16384 + kc);
        const f32x4 wa = *(const f32x4*)(wp + kc);
        const f32x4 wb = *(const f32x4*)(wp + kc + 4);
        const bf16x8 bfr = cvt8(wa, wb);
        #pragma unroll
        for (int m = 0; m < 8; ++m)
            acc[m] = __builtin_amdgcn_mfma_f32_16x16x32_bf16(afr[m], bfr, acc[m], 0, 0, 0);
    }

    #pragma unroll
    for (int m = 0; m < 8; ++m) {
        const int rbase = m * 16 + (lane >> 4) * 4;
        #pragma unroll
        for (int r = 0; r < 4; ++r)
            out[(size_t)(rbase + r) * 1024 + n0 + m16] = acc[m][r];
    }
}

// ---------------------------------------------------------------------------
// prep: embed lookup + split3 (blocks 0..127) and h0 split3 (blocks 128..383)
__global__ void prep_k(const int* __restrict__ word, const float* __restrict__ emb,
                       const float* __restrict__ h0,
                       short* __restrict__ xh, short* __restrict__ xm, short* __restrict__ xl,
                       short* __restrict__ h0h, short* __restrict__ h0m, short* __restrict__ h0l)
{
    const int blk = blockIdx.x, t = threadIdx.x;
    const float* src; short *dh, *dm, *dl; size_t off;
    if (blk < 128) {
        src = emb + (size_t)word[blk] * H; off = (size_t)blk * H;
        dh = xh; dm = xm; dl = xl;
    } else {
        const int i = blk - 128;
        src = h0 + (size_t)i * H; off = (size_t)i * H;
        dh = h0h; dm = h0m; dl = h0l;
    }
    const float4 v = ((const float4*)src)[t];
    short4v sh, sm, sl;
    S3 s;
    s = split3(v.x); sh.x = s.h; sm.x = s.m; sl.x = s.l;
    s = split3(v.y); sh.y = s.h; sm.y = s.m; sl.y = s.l;
    s = split3(v.z); sh.z = s.h; sm.z = s.m; sl.z = s.l;
    s = split3(v.w); sh.w = s.h; sm.w = s.m; sl.w = s.l;
    *(short4v*)(dh + off + t * 4) = sh;
    *(short4v*)(dm + off + t * 4) = sm;
    *(short4v*)(dl + off + t * 4) = sl;
}

// sum 8 partials + biases -> LSTM cell -> h (fp32), c (fp32), x splits (bf16)
__global__ void lstm_cell_k(const float* __restrict__ part,
                            const float* __restrict__ bih, const float* __restrict__ bhh,
                            const float* __restrict__ c0,
                            float* __restrict__ h_out, float* __restrict__ c_out,
                            short* __restrict__ xh, short* __restrict__ xm,
                            short* __restrict__ xl)
{
    const int idx = blockIdx.x * 256 + threadIdx.x;   // < 128*1024
    const int b = idx >> 10, hh = idx & 1023;
    const size_t base = (size_t)b * 4096;
    float g[4];
    #pragma unroll
    for (int j = 0; j < 4; ++j) {
        const int o = hh + j * H;
        float s = bih[o] + bhh[o];
        #pragma unroll
        for (int i = 0; i < 8; ++i) s += part[base + o + (size_t)i * 524288];
        g[j] = s;
    }
    const float c = sigf(g[1]) * c0[idx] + sigf(g[0]) * tanhf(g[2]);
    const float h = sigf(g[3]) * tanhf(c);
    c_out[idx] = c;
    h_out[idx] = h;
    const S3 s = split3(h);
    xh[idx] = s.h; xm[idx] = s.m; xl[idx] = s.l;
}

// fused: finish p from 16 t1pre partials -> window -> scores -> softmax*gauss
// -> a (out) and ctx (bf16)
__global__ void attn_ctx_k(const float* __restrict__ part, const float* __restrict__ b1,
                           const float* __restrict__ w2v, const float* __restrict__ b2,
                           const int* __restrict__ Sptr,
                           const float* __restrict__ x, const float* __restrict__ enc,
                           float* __restrict__ a_out, short* __restrict__ ctxb)
{
    __shared__ float red[256];
    __shared__ float so[H];
    __shared__ float swred[4][MAXW];
    __shared__ float ssc[MAXW];
    __shared__ float sa[MAXW];
    __shared__ float sp;
    __shared__ int sw0, sw1;
    const int b = blockIdx.x, t = threadIdx.x;
    const int lane = t & 63, wvv = t >> 6;

    {
        const float* pa = part + (size_t)b * 512;
        float v = 0.f;
        #pragma unroll
        for (int jj = 0; jj < 2; ++jj) {
            const int j = t + jj * 256;
            float sgm = b1[j];
            #pragma unroll
            for (int i = 0; i < 16; ++i) sgm += pa[j + (size_t)i * 65536];
            v += tanhf(sgm) * w2v[j];
        }
        red[t] = v;
        __syncthreads();
        for (int s = 128; s > 0; s >>= 1) {
            if (t < s) red[t] += red[t + s];
            __syncthreads();
        }
        if (t == 0) {
            const float S = (float)Sptr[0];
            const float sv = S * sigf(red[0] + b2[0]);
            sp  = sv;
            sw0 = (int)rintf(fmaxf(sv - (float)WSZ, 0.f));
            sw1 = (int)rintf(fminf(sv + (float)WSZ, S - 1.f));
        }
    }
    for (int h = t; h < H; h += 256) so[h] = x[(size_t)b * H + h];
    __syncthreads();
    const int w0 = sw0, w1e = sw1;
    const float pbv = sp;

    float ps[MAXW];
    #pragma unroll
    for (int w = 0; w < MAXW; ++w) ps[w] = 0.f;
    for (int h4 = t; h4 < H / 4; h4 += 256) {
        const float4 o = ((const float4*)so)[h4];
        #pragma unroll
        for (int w = 0; w < MAXW; ++w) {
            const int idx = w0 + w;
            if (idx <= w1e) {
                const float4 e = *(const float4*)(enc + ((size_t)idx * B + b) * H + h4 * 4);
                ps[w] += o.x * e.x + o.y * e.y + o.z * e.z + o.w * e.w;
            }
        }
    }
    #pragma unroll
    for (int w = 0; w < MAXW; ++w) {
        float v = ps[w];
        for (int off = 32; off > 0; off >>= 1) v += __shfl_down(v, off);
        if (lane == 0) swred[wvv][w] = v;
    }
    __syncthreads();
    if (t == 0) {
        float m = -1e30f;
        for (int w = 0; w < MAXW; ++w) {
            const float s = swred[0][w] + swred[1][w] + swred[2][w] + swred[3][w];
            ssc[w] = s;
            m = fmaxf(m, s);
        }
        float den = 0.f;
        for (int w = 0; w < MAXW; ++w) den += expf(ssc[w] - m);
        for (int w = 0; w < MAXW; ++w) {
            const int idx = w0 + w;
            const float gauss = (idx <= w1e) ? expf(((float)idx - pbv) / 50.0f) : 0.f;
            sa[w] = expf(ssc[w] - m) / den * gauss;
        }
    }
    __syncthreads();
    if (t < MAXW) a_out[b * MAXW + t] = sa[t];
    for (int h4 = t; h4 < H / 4; h4 += 256) {
        float4 acc = {0.f, 0.f, 0.f, 0.f};
        #pragma unroll
        for (int w = 0; w < MAXW; ++w) {
            const int idx = w0 + w;
            if (idx <= w1e) {
                const float4 e = *(const float4*)(enc + ((size_t)idx * B + b) * H + h4 * 4);
                acc.x += sa[w] * e.x; acc.y += sa[w] * e.y;
                acc.z += sa[w] * e.z; acc.w += sa[w] * e.w;
            }
        }
        short4v s;
        s.x = (short)rnebf(acc.x); s.y = (short)rnebf(acc.y);
        s.z = (short)rnebf(acc.z); s.w = (short)rnebf(acc.w);
        *(short4v*)(ctxb + (size_t)b * H + h4 * 4) = s;
    }
}

// sum 16 fc1 partials + bias -> tanh -> o2 (fp32, d_out) + o2b (bf16)
__global__ void fc1_fin_k(const float* __restrict__ part, const float* __restrict__ bias,
                          float* __restrict__ o2, short* __restrict__ o2b)
{
    const int idx = blockIdx.x * 256 + threadIdx.x;   // < 128*1024
    const int n = idx & 1023;
    float v = bias[n];
    #pragma unroll
    for (int i = 0; i < 16; ++i) v += part[idx + (size_t)i * 131072];
    v = tanhf(v);
    o2[idx] = v;
    o2b[idx] = (short)rnebf(v);
}

// fused fc2-finish + log_softmax: row = p0 + p1 + bias held in registers.
__global__ __launch_bounds__(1024) void lsm_k(
    const float* __restrict__ p0, const float* __restrict__ p1,
    const float* __restrict__ bias, float* __restrict__ y)
{
    __shared__ float sm[16], ss[16], slse;
    const int b = blockIdx.x, t = threadIdx.x;
    const float* r0 = p0 + (size_t)b * V;
    const float* r1 = p1 + (size_t)b * V;
    float* yrow = y + (size_t)b * V;

    f32x4 r[8];
    float m = -1e30f, s = 0.f;
    #pragma unroll
    for (int i = 0; i < 8; ++i) {
        const int v4 = t + i * 1024;
        if (v4 < V / 4) {
            const f32x4 a = ((const f32x4*)r0)[v4];
            const f32x4 c = ((const f32x4*)r1)[v4];
            const f32x4 bv = ((const f32x4*)bias)[v4];
            f32x4 q;
            q.x = a.x + c.x + bv.x; q.y = a.y + c.y + bv.y;
            q.z = a.z + c.z + bv.z; q.w = a.w + c.w + bv.w;
            r[i] = q;
            const float mm = fmaxf(fmaxf(q.x, q.y), fmaxf(q.z, q.w));
            if (mm > m) { s *= expf(m - mm); m = mm; }
            s += expf(q.x - m) + expf(q.y - m) + expf(q.z - m) + expf(q.w - m);
        }
    }
    for (int off = 32; off > 0; off >>= 1) {
        const float mo = __shfl_down(m, off), so = __shfl_down(s, off);
        const float mn = fmaxf(m, mo);
        s = s * expf(m - mn) + so * expf(mo - mn);
        m = mn;
    }
    const int wv = t >> 6, lane = t & 63;
    if (lane == 0) { sm[wv] = m; ss[wv] = s; }
    __syncthreads();
    if (t == 0) {
        float M = sm[0], S = ss[0];
        for (int i = 1; i < 16; ++i) {
            const float mn = fmaxf(M, sm[i]);
            S = S * expf(M - mn) + ss[i] * expf(sm[i] - mn);
            M = mn;
        }
        slse = M + logf(S);
    }
    __syncthreads();
    const float lse = slse;
    #pragma unroll
    for (int i = 0; i < 8; ++i) {
        const int v4 = t + i * 1024;
        if (v4 < V / 4) {
            f32x4 q = r[i];
            q.x -= lse; q.y -= lse; q.z -= lse; q.w -= lse;
            ((f32x4*)yrow)[v4] = q;
        }
    }
}

} // namespace

extern "C" void kernel_launch(void* const* d_in, const int* in_sizes, int n_in,
                              void* d_out, int out_size, void* d_ws, size_t ws_size,
                              hipStream_t stream)
{
    const int*   Sp   = (const int*)d_in[0];
    const float* enc  = (const float*)d_in[1];
    const int*   word = (const int*)d_in[2];
    const float* h0   = (const float*)d_in[3];
    const float* c0   = (const float*)d_in[4];
    const float* emb  = (const float*)d_in[5];
    const float* Wih  = (const float*)d_in[6];
    const float* Whh  = (const float*)d_in[7];
    const float* bih  = (const float*)d_in[8];
    const float* bhh  = (const float*)d_in[9];
    const float* aw1  = (const float*)d_in[10];
    const float* ab1  = (const float*)d_in[11];
    const float* aw2  = (const float*)d_in[12];
    const float* ab2  = (const float*)d_in[13];
    const float* f1w  = (const float*)d_in[14];
    const float* f1b  = (const float*)d_in[15];
    const float* f2w  = (const float*)d_in[16];
    const float* f2b  = (const float*)d_in[17];

    float* outp = (float*)d_out;
    float* y    = outp;                       // 128*32000
    float* o2   = y  + (size_t)B * V;         // 128*1024
    float* hN   = o2 + (size_t)B * H;         // 2*128*1024
    float* cN   = hN + 2 * (size_t)B * H;     // 2*128*1024
    float* aO   = cN + 2 * (size_t)B * H;     // 128*21

    char* wsp = (char*)d_ws;
    short* xh   = (short*)wsp;  wsp += (size_t)B * H * 2;
    short* xm   = (short*)wsp;  wsp += (size_t)B * H * 2;
    short* xl   = (short*)wsp;  wsp += (size_t)B * H * 2;
    short* h0h  = (short*)wsp;  wsp += (size_t)2 * B * H * 2;
    short* h0m  = (short*)wsp;  wsp += (size_t)2 * B * H * 2;
    short* h0l  = (short*)wsp;  wsp += (size_t)2 * B * H * 2;
    short* ctxb = (short*)wsp;  wsp += (size_t)B * H * 2;
    short* o2b  = (short*)wsp;  wsp += (size_t)B * H * 2;
    float* part = (float*)wsp;  wsp += (size_t)16 * B * 4 * H * 4;  // 32 MB
    float* pf2  = (float*)wsp;  wsp += (size_t)2 * B * V * 4;       // 32.8 MB

    prep_k<<<dim3(384), dim3(256), 0, stream>>>(word, emb, h0, xh, xm, xl, h0h, h0m, h0l);

    for (int l = 0; l < 2; ++l) {
        gemm_x3<<<dim3(64, 8), dim3(256), 0, stream>>>(
            xh, xm, xl,
            h0h + (size_t)l * B * H, h0m + (size_t)l * B * H, h0l + (size_t)l * B * H,
            Wih + (size_t)l * 4 * H * H, Whh + (size_t)l * 4 * H * H,
            4 * H, 256, 2, part);
        lstm_cell_k<<<dim3(B * H / 256), dim3(256), 0, stream>>>(
            part, bih + (size_t)l * 4 * H, bhh + (size_t)l * 4 * H,
            c0 + (size_t)l * B * H,
            hN + (size_t)l * B * H, cN + (size_t)l * B * H, xh, xm, xl);
    }

    const float* hfin = hN + (size_t)B * H;  // last layer h (fp32)

    // attn position pre-GEMM: t1pre = h @ w1^T (split3 MFMA, 16 K-partials)
    gemm_x3<<<dim3(8, 16), dim3(256), 0, stream>>>(
        xh, xm, xl, xh, xm, xl, aw1, aw1, 512, 64, 4, part);
    attn_ctx_k<<<dim3(B), dim3(256), 0, stream>>>(
        part, ab1, aw2, ab2, Sp, hfin, enc, aO, ctxb);

    // fc1: [ctx | out] @ f1w^T -> 16 split-K partials -> tanh
    fc1_gemm<<<dim3(16, 16), dim3(256), 0, stream>>>(ctxb, xh, f1w, part);
    fc1_fin_k<<<dim3(B * H / 256), dim3(256), 0, stream>>>(part, f1b, o2, o2b);

    // fc2: o2 @ f2w^T -> 2 K-partials (coalesced LDS-staged W)
    fc2_gemm<<<dim3(V / 64, 2), dim3(256), 0, stream>>>(o2b, f2w, pf2);

    // fused fc2-finish (+bias) and log_softmax
    lsm_k<<<dim3(B), dim3(1024), 0, stream>>>(pf2, pf2 + (size_t)B * V, f2b, y);
}